// Round 7
// baseline (759.642 us; speedup 1.0000x reference)
//
#include <hip/hip_runtime.h>
#include <math.h>
#include <stdint.h>

// SoftAttention B=32, L=1024, D=256 fp32.
// R7: occupancy restructure. S = Qhi·Khi (bf16 MFMA) + [Qlo8·Khi8 + Qhi8·Klo8]
// (fp8 e4m3 MFMA, lo-parts pre-scaled x256; correction ~0.3 logits needs only
// ~4 bits). Only K-hi bf16 (32 KB) + P (16.5 KB) in LDS -> 2 blocks/CU; only
// Q-hi (64 VGPRs) pinned in registers -> 4 waves/SIMD via launch_bounds(512,4).
// Q8/K8/V fragments stream from L2 (XCD-pinned swizzle keeps them L2-hot).

#define NB    32
#define SEQ   1024
#define DIM   256
#define BM    128
#define BN    64
#define SHIFT 60.0f
#define PS    1032   // Ph ushort stride per koct: 2064 B (16B-aligned, 4-bank shift)

typedef unsigned int uint;
typedef unsigned short ushort;
typedef unsigned char uchar;
typedef __attribute__((ext_vector_type(8)))  short short8;
typedef __attribute__((ext_vector_type(16))) float f32x16;
typedef __attribute__((ext_vector_type(2)))  long long ll2;

// ---- ws layout (bytes) ----
// per tensor: HI bf16 octets [doct32][seq][8]      16 MB
//             F8 fp8 hi|lo  [doct32][seq][16B]     16 MB
//             T  bf16 V-T   [soct128][dim][8]      16 MB
#define HI_BATCH   (32 * 1024 * 8)                  // ushorts
#define HI_TENSOR  ((size_t)NB * HI_BATCH)          // 8.4M ushorts = 16 MB
#define F8_BATCH   (32 * 1024 * 16)                 // bytes
#define F8_TENSOR  ((size_t)NB * F8_BATCH)          // 16 MB
#define T_BATCH    (128 * 256 * 8)                  // ushorts
#define T_TENSOR   ((size_t)NB * T_BATCH)           // 16 MB
#define WS_NEED    (2 * (HI_TENSOR * 2 + F8_TENSOR + T_TENSOR * 2))  // 96 MB

__device__ __forceinline__ ushort bf16_rn(float x) {
    union { float f; uint u; } v; v.f = x;
    uint r = v.u + 0x7fffu + ((v.u >> 16) & 1u);
    return (ushort)(r >> 16);
}
__device__ __forceinline__ float bf16_to_f(ushort h) {
    union { uint u; float f; } v; v.u = ((uint)h) << 16;
    return v.f;
}
__device__ __forceinline__ void gl_lds16(const ushort* g, ushort* l) {
    __builtin_amdgcn_global_load_lds(
        (const __attribute__((address_space(1))) void*)g,
        (__attribute__((address_space(3))) void*)l, 16, 0, 0);
}

// ---------------- pre-pass: fp32 -> {bf16-hi octets, fp8 hi|lo octets, V-T} ----
#define TSTR 260
__global__ __launch_bounds__(256)
void prepass(const float* __restrict__ A, const float* __restrict__ Bt,
             ushort* __restrict__ aHI, ushort* __restrict__ bHI,
             uchar*  __restrict__ a8,  uchar*  __restrict__ b8,
             ushort* __restrict__ aT,  ushort* __restrict__ bT)
{
    const int tensor = blockIdx.z;
    const float* src = tensor ? Bt : A;
    ushort* hi = tensor ? bHI : aHI;
    uchar*  f8 = tensor ? b8  : a8;
    ushort* tp = tensor ? bT  : aT;
    const int batch = blockIdx.y;
    const int s0    = blockIdx.x * 64;
    const int tid   = threadIdx.x;

    __shared__ float tile[64 * TSTR];   // 64 rows x 256 dims fp32, 66.6 KB

    // coalesced load
    const float* sb = src + ((size_t)batch * SEQ + s0) * DIM;
    #pragma unroll
    for (int i = 0; i < 16; ++i) {
        int idx = tid + i * 256;         // float4 index, 4096 total
        int r = idx >> 6, c = idx & 63;
        float4 v = *((const float4*)(sb + (size_t)r * DIM) + c);
        *(float4*)&tile[r * TSTR + c * 4] = v;
    }
    __syncthreads();

    // phase 2: hi-bf16 + fp8 hi|lo octets. wave w -> docts w*8..w*8+7, lane = seq row.
    {
        const int w = tid >> 6, lane = tid & 63;
        ushort* hib = hi + (size_t)batch * HI_BATCH;
        uchar*  f8b = f8 + (size_t)batch * F8_BATCH;
        #pragma unroll
        for (int dd = 0; dd < 8; ++dd) {
            const int d = w * 8 + dd;
            float4 x0 = *(const float4*)&tile[lane * TSTR + d * 8];
            float4 x1 = *(const float4*)&tile[lane * TSTR + d * 8 + 4];
            float f[8] = {x0.x, x0.y, x0.z, x0.w, x1.x, x1.y, x1.z, x1.w};
            short8 hv;
            float hf[8], lf[8];
            #pragma unroll
            for (int j = 0; j < 8; ++j) {
                ushort h = bf16_rn(f[j]);
                hv[j] = (short)h;
                hf[j] = bf16_to_f(h);
                lf[j] = (f[j] - hf[j]) * 256.0f;   // scale lo into e4m3 range
            }
            uint h0 = __builtin_amdgcn_cvt_pk_fp8_f32(hf[0], hf[1], 0u, false);
            h0      = __builtin_amdgcn_cvt_pk_fp8_f32(hf[2], hf[3], h0, true);
            uint h1 = __builtin_amdgcn_cvt_pk_fp8_f32(hf[4], hf[5], 0u, false);
            h1      = __builtin_amdgcn_cvt_pk_fp8_f32(hf[6], hf[7], h1, true);
            uint l0 = __builtin_amdgcn_cvt_pk_fp8_f32(lf[0], lf[1], 0u, false);
            l0      = __builtin_amdgcn_cvt_pk_fp8_f32(lf[2], lf[3], l0, true);
            uint l1 = __builtin_amdgcn_cvt_pk_fp8_f32(lf[4], lf[5], 0u, false);
            l1      = __builtin_amdgcn_cvt_pk_fp8_f32(lf[6], lf[7], l1, true);
            *(short8*)(hib + (size_t)d * 8192 + (size_t)(s0 + lane) * 8) = hv;
            uint4 pk; pk.x = h0; pk.y = h1; pk.z = l0; pk.w = l1;
            *(uint4*)(f8b + (size_t)d * 16384 + (size_t)(s0 + lane) * 16) = pk;
        }
    }

    // phase 3: transposed V-hi [soct][dim][8]; d = tid (0..255)
    {
        ushort* tpb = tp + (size_t)batch * T_BATCH;
        const int d = tid;
        #pragma unroll
        for (int so = 0; so < 8; ++so) {
            short8 hv;
            #pragma unroll
            for (int j = 0; j < 8; ++j)
                hv[j] = (short)bf16_rn(tile[(so * 8 + j) * TSTR + d]);
            *(short8*)(tpb + (size_t)(blockIdx.x * 8 + so) * 2048 + (size_t)d * 8) = hv;
        }
    }
}

// ---------------- main kernel: 512 thr, 2 blocks/CU, 4 waves/SIMD ----------------
__global__ __launch_bounds__(512, 4)
void attend4(const ushort* __restrict__ aHI, const ushort* __restrict__ bHI,
             const uchar*  __restrict__ a8,  const uchar*  __restrict__ b8,
             const ushort* __restrict__ aT,  const ushort* __restrict__ bT,
             const int*    __restrict__ ma,  const int*    __restrict__ mb,
             float*        __restrict__ out)
{
    __shared__ __align__(16) ushort KhiS[32 * 512];  // [doct32][key64][8]  32 KB
    __shared__ __align__(16) ushort Ph[8 * PS];      // [koct8][qrow128][8] 16.5 KB

    // XCD-pinning swizzle (R6): 8 row-blocks of one (batch,dir) share an XCD.
    const int bx   = blockIdx.x;        // 0..511
    const int xcd  = bx & 7;
    const int slot = bx >> 3;
    const int rb   = slot & 7;
    const int pg   = slot >> 3;
    const int pair = xcd + 8 * pg;
    const int batch = pair >> 1;
    const int dir   = pair & 1;
    const int row0  = rb * BM;

    const ushort* xhi = dir ? bHI : aHI;
    const uchar*  x8  = dir ? b8  : a8;
    const ushort* yhi = dir ? aHI : bHI;
    const uchar*  y8  = dir ? a8  : b8;
    const ushort* yt  = dir ? aT  : bT;
    const int*    mx  = dir ? mb  : ma;
    const int*    my  = dir ? ma  : mb;
    float* o = out + (size_t)dir * NB * SEQ * DIM;

    const int tid  = threadIdx.x;
    const int lane = tid & 63;
    const int wave = tid >> 6;     // 0..7
    const int l31  = lane & 31;
    const int lh   = lane >> 5;
    const int rw   = wave >> 1;    // row block 0..3
    const int cw   = wave & 1;     // key half / dim half

    const ushort* xhib = xhi + (size_t)batch * HI_BATCH;
    const uchar*  x8b  = x8  + (size_t)batch * F8_BATCH;
    const ushort* yhib = yhi + (size_t)batch * HI_BATCH;
    const uchar*  y8b  = y8  + (size_t)batch * F8_BATCH;
    const ushort* ytb  = yt  + (size_t)batch * T_BATCH;

    // K-hi staging: wave w stages docts w*4..w*4+3 (1 KB chunks, lane*16B)
    const ushort* ksrc = yhib + (size_t)(wave * 4) * 8192 + (size_t)lane * 8;
    ushort*       kdst = KhiS + wave * 4 * 512 + lane * 8;
    #pragma unroll
    for (int i = 0; i < 4; ++i) gl_lds16(ksrc + (size_t)i * 8192, kdst + i * 512);

    // Q-hi fragments in registers (the only pinned operand): m=l31, k-oct=2kk+lh
    const int qrow = row0 + rw * 32 + l31;
    short8 qhi[16];
    {
        const ushort* qb = xhib + (size_t)lh * 8192 + (size_t)qrow * 8;
        #pragma unroll
        for (int kk = 0; kk < 16; ++kk)
            qhi[kk] = *(const short8*)(qb + (size_t)(2 * kk) * 8192);
    }
    const uchar* q8base = x8b + (size_t)lh * 16384 + (size_t)qrow * 16;

    f32x16 oacc[4];
    #pragma unroll
    for (int t = 0; t < 4; ++t)
        #pragma unroll
        for (int r = 0; r < 16; ++r) oacc[t][r] = 0.f;
    float lsum[16];
    #pragma unroll
    for (int r = 0; r < 16; ++r) lsum[r] = 0.f;

    __syncthreads();   // K(0) staged

    const int key  = cw * 32 + l31;
    const int koct = key >> 3, kj = key & 7;

    for (int nt = 0; nt < SEQ / BN; ++nt) {
        const int key0 = nt * BN;
        const float mkv = (float)my[batch * SEQ + key0 + key];

        // ---- S: a1 = Qhi·Khi (bf16); a2 = Qlo8·Khi8 + Qhi8·Klo8 (fp8, x256) ----
        f32x16 a1, a2;
        #pragma unroll
        for (int r = 0; r < 16; ++r) { a1[r] = 0.f; a2[r] = 0.f; }
        const uchar* k8base = y8b + (size_t)lh * 16384 + (size_t)(key0 + key) * 16;
        #pragma unroll
        for (int kk = 0; kk < 16; ++kk) {
            short8 bhi = *(const short8*)&KhiS[(2 * kk + lh) * 512 + key * 8];
            ll2 k8 = *(const ll2*)(k8base + (size_t)(2 * kk) * 16384); // x=hi8, y=lo8
            ll2 q8 = *(const ll2*)(q8base + (size_t)(2 * kk) * 16384);
            a1 = __builtin_amdgcn_mfma_f32_32x32x16_bf16(qhi[kk], bhi, a1, 0, 0, 0);
            a2 = __builtin_amdgcn_mfma_f32_32x32x16_fp8_fp8(q8.y, k8.x, a2, 0, 0, 0);
            a2 = __builtin_amdgcn_mfma_f32_32x32x16_fp8_fp8(q8.x, k8.y, a2, 0, 0, 0);
        }

        // ---- fixed-shift exp + pack P-hi ----
        #pragma unroll
        for (int r = 0; r < 16; ++r) {
            float s = a1[r] + a2[r] * 0.00390625f;   // /256 undoes lo-scaling
            float p = __expf(s - SHIFT) * mkv;
            lsum[r] += p;
            int qr = rw * 32 + (r & 3) + ((r >> 2) << 3) + (lh << 2);
            Ph[koct * PS + qr * 8 + kj] = bf16_rn(p);
        }
        __syncthreads();   // P visible; KhiS free

        // prefetch K-hi(nt+1) — drained at the post-PV barrier
        if (nt + 1 < SEQ / BN) {
            const ushort* ks = ksrc + (size_t)(key0 + BN) * 8;
            #pragma unroll
            for (int i = 0; i < 4; ++i) gl_lds16(ks + (size_t)i * 8192, kdst + i * 512);
        }

        // ---- PV: oacc += Phi·Vhi, V-frags straight from global (L2-hot) ----
        const int prow = (rw * 32 + l31) * 8;
        #pragma unroll
        for (int kb = 0; kb < 4; ++kb) {
            short8 pa = *(const short8*)&Ph[(2 * kb + lh) * PS + prow];
            const ushort* vb = ytb + (size_t)(nt * 8 + 2 * kb + lh) * 2048;
            #pragma unroll
            for (int t = 0; t < 4; ++t) {
                int dim = cw * 128 + t * 32 + l31;
                short8 vf = *(const short8*)(vb + (size_t)dim * 8);
                oacc[t] = __builtin_amdgcn_mfma_f32_32x32x16_bf16(pa, vf, oacc[t], 0, 0, 0);
            }
        }
        __syncthreads();   // Ph free; K(nt+1) drained
    }

    // ---- epilogue: reduce l (overlay scratch on Ph), normalize, store ----
    float* lp = (float*)Ph;          // Ph dead after final barrier
    float* iv = lp + 2 * BM;
    #pragma unroll
    for (int r = 0; r < 16; ++r) {
        float v = lsum[r];
        v += __shfl_xor(v, 1, 64);
        v += __shfl_xor(v, 2, 64);
        v += __shfl_xor(v, 4, 64);
        v += __shfl_xor(v, 8, 64);
        v += __shfl_xor(v, 16, 64);
        if (l31 == 0) {
            int row = rw * 32 + (r & 3) + ((r >> 2) << 3) + (lh << 2);
            lp[cw * BM + row] = v;
        }
    }
    __syncthreads();
    if (tid < BM) {
        float l = lp[tid] + lp[BM + tid];
        int valid = mx[batch * SEQ + row0 + tid];
        iv[tid] = (valid != 0 && l > 0.f) ? 1.f / l : 0.f;
    }
    __syncthreads();

    float* ob = o + ((size_t)batch * SEQ + row0) * DIM;
    #pragma unroll
    for (int r = 0; r < 16; ++r) {
        int rloc = rw * 32 + (r & 3) + ((r >> 2) << 3) + (lh << 2);
        float inv = iv[rloc];
        #pragma unroll
        for (int t = 0; t < 4; ++t) {
            int d = cw * 128 + t * 32 + l31;
            ob[(size_t)rloc * DIM + d] = oacc[t][r] * inv;
        }
    }
}

// ---------------- fallback (R2 kernel, known-good) if ws too small ----------------
#define F_KS_STR 520
#define F_P_STR  136
#define F_BM 64
#define F_BN 64
__global__ __launch_bounds__(256, 1)
void attend_mfma(const float* __restrict__ X, const float* __restrict__ Y,
                 const int* __restrict__ mx, const int* __restrict__ my,
                 float* __restrict__ out)
{
    __shared__ ushort Ks[F_BN * F_KS_STR];
    __shared__ ushort Ps[F_BM * F_P_STR];
    __shared__ float  mk[F_BN];
    __shared__ float  lpart[2][F_BM];
    __shared__ float  invs[F_BM];

    const int tid = threadIdx.x, lane = tid & 63, wave = tid >> 6;
    const int l31 = lane & 31, lh = lane >> 5;
    const int rw = wave >> 1, cw = wave & 1;
    const int batch = blockIdx.y, row0 = blockIdx.x * F_BM;
    const float* Xb = X + (size_t)batch * SEQ * DIM;
    const float* Yb = Y + (size_t)batch * SEQ * DIM;

    float4 kreg[16]; int mreg = 0;
    #pragma unroll
    for (int i = 0; i < 16; ++i) {
        int idx = tid + (i << 8); int r = idx >> 6, c4 = idx & 63;
        kreg[i] = *((const float4*)(Yb + (size_t)r * DIM) + c4);
    }
    if (tid < F_BN) mreg = my[batch * SEQ + tid];

    short8 qhi[16], qlo[16];
    {
        const float* qrow = Xb + (size_t)(row0 + rw * 32 + l31) * DIM + lh * 8;
        #pragma unroll
        for (int kk = 0; kk < 16; ++kk) {
            const float* p = qrow + kk * 16;
            float4 x0 = *(const float4*)p; float4 x1 = *(const float4*)(p + 4);
            float xs[8] = {x0.x, x0.y, x0.z, x0.w, x1.x, x1.y, x1.z, x1.w};
            #pragma unroll
            for (int j = 0; j < 8; ++j) {
                ushort h = bf16_rn(xs[j]);
                qhi[kk][j] = (short)h;
                qlo[kk][j] = (short)bf16_rn(xs[j] - bf16_to_f(h));
            }
        }
    }
    f32x16 oacc[4];
    #pragma unroll
    for (int t = 0; t < 4; ++t)
        #pragma unroll
        for (int r = 0; r < 16; ++r) oacc[t][r] = 0.f;
    float lsum[16];
    #pragma unroll
    for (int r = 0; r < 16; ++r) lsum[r] = 0.f;

    for (int nt = 0; nt < SEQ / F_BN; ++nt) {
        if (nt) __syncthreads();
        #pragma unroll
        for (int i = 0; i < 16; ++i) {
            int idx = tid + (i << 8); int r = idx >> 6, c4 = idx & 63;
            float f[4] = {kreg[i].x, kreg[i].y, kreg[i].z, kreg[i].w};
            ushort hh[4], ll[4];
            #pragma unroll
            for (int q = 0; q < 4; ++q) { hh[q] = bf16_rn(f[q]); ll[q] = bf16_rn(f[q] - bf16_to_f(hh[q])); }
            ushort4 hv; hv.x=hh[0];hv.y=hh[1];hv.z=hh[2];hv.w=hh[3];
            ushort4 lv; lv.x=ll[0];lv.y=ll[1];lv.z=ll[2];lv.w=ll[3];
            *(ushort4*)&Ks[r * F_KS_STR + c4 * 4] = hv;
            *(ushort4*)&Ks[r * F_KS_STR + 256 + c4 * 4] = lv;
        }
        if (tid < F_BN) mk[tid] = (float)mreg;
        __syncthreads();
        if (nt + 1 < SEQ / F_BN) {
            const float* Ybn = Yb + (size_t)(nt + 1) * F_BN * DIM;
            #pragma unroll
            for (int i = 0; i < 16; ++i) {
                int idx = tid + (i << 8); int r = idx >> 6, c4 = idx & 63;
                kreg[i] = *((const float4*)(Ybn + (size_t)r * DIM) + c4);
            }
            if (tid < F_BN) mreg = my[batch * SEQ + (nt + 1) * F_BN + tid];
        }
        f32x16 a1, a2, a3;
        #pragma unroll
        for (int r = 0; r < 16; ++r) { a1[r]=0.f; a2[r]=0.f; a3[r]=0.f; }
        const int krow = (cw * 32 + l31) * F_KS_STR;
        #pragma unroll
        for (int kk = 0; kk < 16; ++kk) {
            int col = kk * 16 + lh * 8;
            short8 bhi = *(const short8*)&Ks[krow + col];
            short8 blo = *(const short8*)&Ks[krow + 256 + col];
            a1 = __builtin_amdgcn_mfma_f32_32x32x16_bf16(qhi[kk], bhi, a1, 0, 0, 0);
            a2 = __builtin_amdgcn_mfma_f32_32x32x16_bf16(qlo[kk], bhi, a2, 0, 0, 0);
            a3 = __builtin_amdgcn_mfma_f32_32x32x16_bf16(qhi[kk], blo, a3, 0, 0, 0);
        }
        const float mkv = mk[cw * 32 + l31];
        #pragma unroll
        for (int r = 0; r < 16; ++r) {
            float s = a1[r] + a2[r] + a3[r];
            float p = __expf(s - SHIFT) * mkv;
            lsum[r] += p;
            ushort ph = bf16_rn(p);
            ushort pl = bf16_rn(p - bf16_to_f(ph));
            int prow = rw * 32 + (r & 3) + ((r >> 2) << 3) + (lh << 2);
            int pcol = cw * 32 + l31;
            Ps[prow * F_P_STR + pcol] = ph;
            Ps[prow * F_P_STR + 64 + pcol] = pl;
        }
        __syncthreads();
        const int prow = (rw * 32 + l31) * F_P_STR;
        #pragma unroll
        for (int kb = 0; kb < 4; ++kb) {
            int pcol = kb * 16 + lh * 8;
            short8 pa_hi = *(const short8*)&Ps[prow + pcol];
            short8 pa_lo = *(const short8*)&Ps[prow + 64 + pcol];
            #pragma unroll
            for (int t = 0; t < 4; ++t) {
                int d0 = cw * 128 + t * 32 + l31;
                short8 vf;
                #pragma unroll
                for (int j = 0; j < 8; ++j) vf[j] = (short)Ks[(pcol + j) * F_KS_STR + d0];
                oacc[t] = __builtin_amdgcn_mfma_f32_32x32x16_bf16(pa_hi, vf, oacc[t], 0, 0, 0);
                oacc[t] = __builtin_amdgcn_mfma_f32_32x32x16_bf16(pa_lo, vf, oacc[t], 0, 0, 0);
            }
        }
    }
    #pragma unroll
    for (int r = 0; r < 16; ++r) {
        float v = lsum[r];
        v += __shfl_xor(v, 1, 64); v += __shfl_xor(v, 2, 64); v += __shfl_xor(v, 4, 64);
        v += __shfl_xor(v, 8, 64); v += __shfl_xor(v, 16, 64);
        if (l31 == 0) {
            int row = rw * 32 + (r & 3) + ((r >> 2) << 3) + (lh << 2);
            lpart[cw][row] = v;
        }
    }
    __syncthreads();
    if (tid < F_BM) {
        float l = lpart[0][tid] + lpart[1][tid];
        int valid = mx[batch * SEQ + row0 + tid];
        invs[tid] = (valid != 0 && l > 0.f) ? 1.f / l : 0.f;
    }
    __syncthreads();
    float* ob = out + ((size_t)batch * SEQ + row0) * DIM;
    #pragma unroll
    for (int r = 0; r < 16; ++r) {
        int rloc = rw * 32 + (r & 3) + ((r >> 2) << 3) + (lh << 2);
        float inv = invs[rloc];
        #pragma unroll
        for (int t = 0; t < 4; ++t) {
            int d = cw * 128 + t * 32 + l31;
            ob[(size_t)rloc * DIM + d] = oacc[t][r] * inv;
        }
    }
}

extern "C" void kernel_launch(void* const* d_in, const int* in_sizes, int n_in,
                              void* d_out, int out_size, void* d_ws, size_t ws_size,
                              hipStream_t stream) {
    const float* a  = (const float*)d_in[0];
    const float* b  = (const float*)d_in[1];
    const int*   ma = (const int*)d_in[2];
    const int*   mb = (const int*)d_in[3];
    float* out = (float*)d_out;

    if (ws_size >= WS_NEED) {
        char* w = (char*)d_ws;
        ushort* aHI = (ushort*)w;
        ushort* bHI = (ushort*)(w + 16 * 1024 * 1024);
        uchar*  a8  = (uchar*) (w + 32 * 1024 * 1024);
        uchar*  b8  = (uchar*) (w + 48 * 1024 * 1024);
        ushort* aT  = (ushort*)(w + 64 * 1024 * 1024);
        ushort* bT  = (ushort*)(w + 80 * 1024 * 1024);

        prepass<<<dim3(SEQ / 64, NB, 2), 256, 0, stream>>>(a, b, aHI, bHI, a8, b8, aT, bT);
        attend4<<<dim3(512, 1, 1), 512, 0, stream>>>(aHI, bHI, a8, b8, aT, bT, ma, mb, out);
    } else {
        float* out_a = out;
        float* out_b = out + (size_t)NB * SEQ * DIM;
        dim3 grid(SEQ / F_BM, NB), block(256);
        attend_mfma<<<grid, block, 0, stream>>>(a, b, ma, mb, out_a);
        attend_mfma<<<grid, block, 0, stream>>>(b, a, mb, ma, out_b);
    }
}

// Round 8
// 398.811 us; speedup vs baseline: 1.9048x; 1.9048x over previous
//
#include <hip/hip_runtime.h>
#include <math.h>
#include <stdint.h>

// SoftAttention B=32, L=1024, D=256 fp32.
// R8: two independent 256-thread blocks per CU (barrier-decoupled), S =
// Qhi·Khi (bf16 MFMA) + [Qlo8·Khi8 + Qhi8·Klo8] (fp8 e4m3, lo prescaled
// x256). K-hi + K8 staged in LDS (78 KB -> 2 blocks/CU); V-frags stream
// from transposed global layout (L2-hot via XCD pinning). launch_bounds
// (256,2) keeps unified VGPR+AGPR within budget -> no spills (R7 lesson).

#define NB    32
#define SEQ   1024
#define DIM   256
#define BM    64
#define BN    64
#define SHIFT 60.0f
#define PS8   528    // Ph ushort stride per koct: (64+2)*8

typedef unsigned int uint;
typedef unsigned short ushort;
typedef unsigned char uchar;
typedef __attribute__((ext_vector_type(8)))  short short8;
typedef __attribute__((ext_vector_type(16))) float f32x16;
typedef __attribute__((ext_vector_type(2)))  long long ll2;

// ---- ws layout ----
#define HI_BATCH   (32 * 1024 * 8)                  // ushorts: [doct32][seq][8]
#define HI_TENSOR  ((size_t)NB * HI_BATCH)          // 16 MB
#define F8_BATCH   (32 * 1024 * 16)                 // bytes: [doct32][seq][16B hi|lo]
#define F8_TENSOR  ((size_t)NB * F8_BATCH)          // 16 MB
#define T_BATCH    (128 * 256 * 8)                  // ushorts: [soct128][dim][8]
#define T_TENSOR   ((size_t)NB * T_BATCH)           // 16 MB
#define WS_NEED    (2 * (HI_TENSOR * 2 + F8_TENSOR + T_TENSOR * 2))  // 96 MB

__device__ __forceinline__ ushort bf16_rn(float x) {
    union { float f; uint u; } v; v.f = x;
    uint r = v.u + 0x7fffu + ((v.u >> 16) & 1u);
    return (ushort)(r >> 16);
}
__device__ __forceinline__ float bf16_to_f(ushort h) {
    union { uint u; float f; } v; v.u = ((uint)h) << 16;
    return v.f;
}
__device__ __forceinline__ void gl_lds16(const ushort* g, ushort* l) {
    __builtin_amdgcn_global_load_lds(
        (const __attribute__((address_space(1))) void*)g,
        (__attribute__((address_space(3))) void*)l, 16, 0, 0);
}

// ---------------- pre-pass: fp32 -> {bf16-hi, fp8 hi|lo, V-T} ----------------
#define TSTR 260
__global__ __launch_bounds__(256)
void prepass(const float* __restrict__ A, const float* __restrict__ Bt,
             ushort* __restrict__ aHI, ushort* __restrict__ bHI,
             uchar*  __restrict__ a8,  uchar*  __restrict__ b8,
             ushort* __restrict__ aT,  ushort* __restrict__ bT)
{
    const int tensor = blockIdx.z;
    const float* src = tensor ? Bt : A;
    ushort* hi = tensor ? bHI : aHI;
    uchar*  f8 = tensor ? b8  : a8;
    ushort* tp = tensor ? bT  : aT;
    const int batch = blockIdx.y;
    const int s0    = blockIdx.x * 32;
    const int tid   = threadIdx.x;

    __shared__ float tile[32 * TSTR];   // 33.3 KB -> 4 blocks/CU

    // LDS tile load (for the transpose phase only)
    const float* sb = src + ((size_t)batch * SEQ + s0) * DIM;
    #pragma unroll
    for (int i = 0; i < 8; ++i) {
        int idx = tid + i * 256;         // float4 index, 2048 total
        int r = idx >> 6, c = idx & 63;
        float4 v = *((const float4*)(sb + (size_t)r * DIM) + c);
        *(float4*)&tile[r * TSTR + c * 4] = v;
    }

    // phase A: hi-bf16 + fp8 hi|lo straight from global (L1/L2-hot, no LDS
    // bank conflicts). tasks = 32 octs x 32 rows, 4 sub-iters.
    {
        ushort* hib = hi + (size_t)batch * HI_BATCH;
        uchar*  f8b = f8 + (size_t)batch * F8_BATCH;
        const int oct = tid >> 3;
        #pragma unroll
        for (int rr = 0; rr < 4; ++rr) {
            const int srow = (tid & 7) + rr * 8;
            const float* rp = src + ((size_t)batch * SEQ + s0 + srow) * DIM + oct * 8;
            float4 x0 = *(const float4*)rp;
            float4 x1 = *(const float4*)(rp + 4);
            float f[8] = {x0.x, x0.y, x0.z, x0.w, x1.x, x1.y, x1.z, x1.w};
            short8 hv;
            float hf[8], lf[8];
            #pragma unroll
            for (int j = 0; j < 8; ++j) {
                ushort h = bf16_rn(f[j]);
                hv[j] = (short)h;
                hf[j] = bf16_to_f(h);
                lf[j] = (f[j] - hf[j]) * 256.0f;   // scale lo into e4m3 range
            }
            uint h0 = __builtin_amdgcn_cvt_pk_fp8_f32(hf[0], hf[1], 0u, false);
            h0      = __builtin_amdgcn_cvt_pk_fp8_f32(hf[2], hf[3], h0, true);
            uint h1 = __builtin_amdgcn_cvt_pk_fp8_f32(hf[4], hf[5], 0u, false);
            h1      = __builtin_amdgcn_cvt_pk_fp8_f32(hf[6], hf[7], h1, true);
            uint l0 = __builtin_amdgcn_cvt_pk_fp8_f32(lf[0], lf[1], 0u, false);
            l0      = __builtin_amdgcn_cvt_pk_fp8_f32(lf[2], lf[3], l0, true);
            uint l1 = __builtin_amdgcn_cvt_pk_fp8_f32(lf[4], lf[5], 0u, false);
            l1      = __builtin_amdgcn_cvt_pk_fp8_f32(lf[6], lf[7], l1, true);
            *(short8*)(hib + (size_t)oct * 8192 + (size_t)(s0 + srow) * 8) = hv;
            uint4 pk; pk.x = h0; pk.y = h1; pk.z = l0; pk.w = l1;
            *(uint4*)(f8b + (size_t)oct * 16384 + (size_t)(s0 + srow) * 16) = pk;
        }
    }
    __syncthreads();

    // phase B: transpose from LDS (lane = d -> conflict-free column reads)
    {
        ushort* tpb = tp + (size_t)batch * T_BATCH;
        const int d = tid;
        #pragma unroll
        for (int so = 0; so < 4; ++so) {
            short8 hv;
            #pragma unroll
            for (int j = 0; j < 8; ++j)
                hv[j] = (short)bf16_rn(tile[(so * 8 + j) * TSTR + d]);
            *(short8*)(tpb + (size_t)(blockIdx.x * 4 + so) * 2048 + (size_t)d * 8) = hv;
        }
    }
}

// ---------------- main kernel: 256 thr, BM=64, 2 blocks/CU ----------------
__global__ __launch_bounds__(256, 2)
void attend5(const ushort* __restrict__ aHI, const ushort* __restrict__ bHI,
             const uchar*  __restrict__ a8,  const uchar*  __restrict__ b8,
             const ushort* __restrict__ aT,  const ushort* __restrict__ bT,
             const int*    __restrict__ ma,  const int*    __restrict__ mb,
             float*        __restrict__ out)
{
    __shared__ __align__(16) ushort KhiS[32 * 512];  // [doct32][key64][8]   32 KB
    __shared__ __align__(16) ushort K8S [32 * 512];  // [doct32][key64][16B] 32 KB
    __shared__ __align__(16) ushort Ph[8 * PS8];     // [koct8][qrow64+2][8] 8.4 KB
    __shared__ float msk[SEQ];                       // 4 KB

    // XCD pinning: all 16 row-blocks of one (batch,dir) share an XCD.
    const int bx   = blockIdx.x;        // 0..1023
    const int xcd  = bx & 7;
    const int slot = bx >> 3;           // 0..127
    const int rb   = slot & 15;         // row-block 0..15
    const int pg   = slot >> 4;         // 0..7
    const int pair = xcd + 8 * pg;      // 0..63
    const int batch = pair >> 1;
    const int dir   = pair & 1;
    const int row0  = rb * BM;

    const ushort* xhi = dir ? bHI : aHI;
    const uchar*  x8  = dir ? b8  : a8;
    const ushort* yhi = dir ? aHI : bHI;
    const uchar*  y8  = dir ? a8  : b8;
    const ushort* yt  = dir ? aT  : bT;
    const int*    mx  = dir ? mb  : ma;
    const int*    my  = dir ? ma  : mb;
    float* o = out + (size_t)dir * NB * SEQ * DIM;

    const int tid  = threadIdx.x;
    const int lane = tid & 63;
    const int wave = tid >> 6;     // 0..3
    const int l31  = lane & 31;
    const int lh   = lane >> 5;
    const int rw   = wave >> 1;    // 0..1 (row 32-block)
    const int cw   = wave & 1;     // 0..1 (key half / dim half)

    const ushort* xhib = xhi + (size_t)batch * HI_BATCH;
    const uchar*  x8b  = x8  + (size_t)batch * F8_BATCH;
    const ushort* yhib = yhi + (size_t)batch * HI_BATCH;
    const uchar*  y8b  = y8  + (size_t)batch * F8_BATCH;
    const ushort* ytb  = yt  + (size_t)batch * T_BATCH;

    // staging: wave w stages docts w*8..w*8+7 for both Khi and K8
    const ushort* ksrc  = yhib + (size_t)(wave * 8) * 8192 + (size_t)lane * 8;
    ushort*       kdst  = KhiS + wave * 8 * 512 + lane * 8;
    const ushort* k8src = (const ushort*)(y8b + (size_t)(wave * 8) * 16384) + (size_t)lane * 8;
    ushort*       k8dst = K8S + wave * 8 * 512 + lane * 8;

    // issue tile 0
    #pragma unroll
    for (int i = 0; i < 8; ++i) {
        gl_lds16(ksrc  + (size_t)i * 8192, kdst  + i * 512);
        gl_lds16(k8src + (size_t)i * 8192, k8dst + i * 512);
    }

    // mask preload
    for (int i = tid; i < SEQ; i += 256) msk[i] = (float)my[batch * SEQ + i];

    // Q-hi fragments in registers: m = l31, k-oct = 2kk+lh
    const int qrow = row0 + rw * 32 + l31;
    short8 qhi[16];
    {
        const ushort* qb = xhib + (size_t)lh * 8192 + (size_t)qrow * 8;
        #pragma unroll
        for (int kk = 0; kk < 16; ++kk)
            qhi[kk] = *(const short8*)(qb + (size_t)(2 * kk) * 8192);
    }
    const uchar* q8base = x8b + (size_t)lh * 16384 + (size_t)qrow * 16;

    f32x16 oacc[4];
    #pragma unroll
    for (int t = 0; t < 4; ++t)
        #pragma unroll
        for (int r = 0; r < 16; ++r) oacc[t][r] = 0.f;
    float lsum[16];
    #pragma unroll
    for (int r = 0; r < 16; ++r) lsum[r] = 0.f;

    __syncthreads();   // tile 0 staged; msk visible

    const int key  = cw * 32 + l31;
    const int koct = key >> 3, kj = key & 7;

    for (int nt = 0; nt < SEQ / BN; ++nt) {
        const int key0 = nt * BN;
        const float mkv = msk[key0 + key];

        // ---- S: a1 = Qhi·Khi (bf16); a2 = Qlo8·Khi8 + Qhi8·Klo8 (fp8 x256) ----
        f32x16 a1, a2;
        #pragma unroll
        for (int r = 0; r < 16; ++r) { a1[r] = 0.f; a2[r] = 0.f; }
        #pragma unroll
        for (int kk = 0; kk < 16; ++kk) {
            short8 bhi = *(const short8*)&KhiS[(2 * kk + lh) * 512 + key * 8];
            ll2 k8 = *(const ll2*)&K8S[(2 * kk + lh) * 512 + key * 8]; // x=hi8,y=lo8
            ll2 q8 = *(const ll2*)(q8base + (size_t)(2 * kk) * 16384);
            a1 = __builtin_amdgcn_mfma_f32_32x32x16_bf16(qhi[kk], bhi, a1, 0, 0, 0);
            a2 = __builtin_amdgcn_mfma_f32_32x32x16_fp8_fp8(q8.y, k8.x, a2, 0, 0, 0);
            a2 = __builtin_amdgcn_mfma_f32_32x32x16_fp8_fp8(q8.x, k8.y, a2, 0, 0, 0);
        }

        // ---- fixed-shift exp + pack P-hi ----
        #pragma unroll
        for (int r = 0; r < 16; ++r) {
            float s = a1[r] + a2[r] * 0.00390625f;   // /256 undoes lo prescale
            float p = __expf(s - SHIFT) * mkv;
            lsum[r] += p;
            int qr = rw * 32 + (r & 3) + ((r >> 2) << 3) + (lh << 2);
            Ph[koct * PS8 + qr * 8 + kj] = bf16_rn(p);
        }
        __syncthreads();   // P visible; K tiles free

        // prefetch K tiles (nt+1) — drained at the post-PV barrier
        if (nt + 1 < SEQ / BN) {
            const ushort* ks  = ksrc  + (size_t)(key0 + BN) * 8;
            const ushort* k8s = k8src + (size_t)(key0 + BN) * 8;
            #pragma unroll
            for (int i = 0; i < 8; ++i) {
                gl_lds16(ks  + (size_t)i * 8192, kdst  + i * 512);
                gl_lds16(k8s + (size_t)i * 8192, k8dst + i * 512);
            }
        }

        // ---- PV: oacc += Phi·Vhi; V-frags from global (coalesced, L2-hot) ----
        const int prow = (rw * 32 + l31) * 8;
        #pragma unroll
        for (int kb = 0; kb < 4; ++kb) {
            short8 pa = *(const short8*)&Ph[(2 * kb + lh) * PS8 + prow];
            const ushort* vb = ytb + (size_t)(nt * 8 + 2 * kb + lh) * 2048;
            #pragma unroll
            for (int t = 0; t < 4; ++t) {
                int dim = cw * 128 + t * 32 + l31;
                short8 vf = *(const short8*)(vb + (size_t)dim * 8);
                oacc[t] = __builtin_amdgcn_mfma_f32_32x32x16_bf16(pa, vf, oacc[t], 0, 0, 0);
            }
        }
        __syncthreads();   // Ph free; K(nt+1) drained
    }

    // ---- epilogue: reduce l (overlay on Ph), normalize, store ----
    float* lp = (float*)Ph;
    float* iv = lp + 2 * BM;
    #pragma unroll
    for (int r = 0; r < 16; ++r) {
        float v = lsum[r];
        v += __shfl_xor(v, 1, 64);
        v += __shfl_xor(v, 2, 64);
        v += __shfl_xor(v, 4, 64);
        v += __shfl_xor(v, 8, 64);
        v += __shfl_xor(v, 16, 64);
        if (l31 == 0) {
            int row = rw * 32 + (r & 3) + ((r >> 2) << 3) + (lh << 2);
            lp[cw * BM + row] = v;
        }
    }
    __syncthreads();
    if (tid < BM) {
        float l = lp[tid] + lp[BM + tid];
        int valid = mx[batch * SEQ + row0 + tid];
        iv[tid] = (valid != 0 && l > 0.f) ? 1.f / l : 0.f;
    }
    __syncthreads();

    float* ob = o + ((size_t)batch * SEQ + row0) * DIM;
    #pragma unroll
    for (int r = 0; r < 16; ++r) {
        int rloc = rw * 32 + (r & 3) + ((r >> 2) << 3) + (lh << 2);
        float inv = iv[rloc];
        #pragma unroll
        for (int t = 0; t < 4; ++t) {
            int d = cw * 128 + t * 32 + l31;
            ob[(size_t)rloc * DIM + d] = oacc[t][r] * inv;
        }
    }
}

// ---------------- fallback (R2 kernel, known-good) if ws too small ----------------
#define F_KS_STR 520
#define F_P_STR  136
#define F_BM 64
#define F_BN 64
__global__ __launch_bounds__(256, 1)
void attend_mfma(const float* __restrict__ X, const float* __restrict__ Y,
                 const int* __restrict__ mx, const int* __restrict__ my,
                 float* __restrict__ out)
{
    __shared__ ushort Ks[F_BN * F_KS_STR];
    __shared__ ushort Ps[F_BM * F_P_STR];
    __shared__ float  mk[F_BN];
    __shared__ float  lpart[2][F_BM];
    __shared__ float  invs[F_BM];

    const int tid = threadIdx.x, lane = tid & 63, wave = tid >> 6;
    const int l31 = lane & 31, lh = lane >> 5;
    const int rw = wave >> 1, cw = wave & 1;
    const int batch = blockIdx.y, row0 = blockIdx.x * F_BM;
    const float* Xb = X + (size_t)batch * SEQ * DIM;
    const float* Yb = Y + (size_t)batch * SEQ * DIM;

    float4 kreg[16]; int mreg = 0;
    #pragma unroll
    for (int i = 0; i < 16; ++i) {
        int idx = tid + (i << 8); int r = idx >> 6, c4 = idx & 63;
        kreg[i] = *((const float4*)(Yb + (size_t)r * DIM) + c4);
    }
    if (tid < F_BN) mreg = my[batch * SEQ + tid];

    short8 qhi[16], qlo[16];
    {
        const float* qrow = Xb + (size_t)(row0 + rw * 32 + l31) * DIM + lh * 8;
        #pragma unroll
        for (int kk = 0; kk < 16; ++kk) {
            const float* p = qrow + kk * 16;
            float4 x0 = *(const float4*)p; float4 x1 = *(const float4*)(p + 4);
            float xs[8] = {x0.x, x0.y, x0.z, x0.w, x1.x, x1.y, x1.z, x1.w};
            #pragma unroll
            for (int j = 0; j < 8; ++j) {
                ushort h = bf16_rn(xs[j]);
                qhi[kk][j] = (short)h;
                qlo[kk][j] = (short)bf16_rn(xs[j] - bf16_to_f(h));
            }
        }
    }
    f32x16 oacc[4];
    #pragma unroll
    for (int t = 0; t < 4; ++t)
        #pragma unroll
        for (int r = 0; r < 16; ++r) oacc[t][r] = 0.f;
    float lsum[16];
    #pragma unroll
    for (int r = 0; r < 16; ++r) lsum[r] = 0.f;

    for (int nt = 0; nt < SEQ / F_BN; ++nt) {
        if (nt) __syncthreads();
        #pragma unroll
        for (int i = 0; i < 16; ++i) {
            int idx = tid + (i << 8); int r = idx >> 6, c4 = idx & 63;
            float f[4] = {kreg[i].x, kreg[i].y, kreg[i].z, kreg[i].w};
            ushort hh[4], ll[4];
            #pragma unroll
            for (int q = 0; q < 4; ++q) { hh[q] = bf16_rn(f[q]); ll[q] = bf16_rn(f[q] - bf16_to_f(hh[q])); }
            ushort4 hv; hv.x=hh[0];hv.y=hh[1];hv.z=hh[2];hv.w=hh[3];
            ushort4 lv; lv.x=ll[0];lv.y=ll[1];lv.z=ll[2];lv.w=ll[3];
            *(ushort4*)&Ks[r * F_KS_STR + c4 * 4] = hv;
            *(ushort4*)&Ks[r * F_KS_STR + 256 + c4 * 4] = lv;
        }
        if (tid < F_BN) mk[tid] = (float)mreg;
        __syncthreads();
        if (nt + 1 < SEQ / F_BN) {
            const float* Ybn = Yb + (size_t)(nt + 1) * F_BN * DIM;
            #pragma unroll
            for (int i = 0; i < 16; ++i) {
                int idx = tid + (i << 8); int r = idx >> 6, c4 = idx & 63;
                kreg[i] = *((const float4*)(Ybn + (size_t)r * DIM) + c4);
            }
            if (tid < F_BN) mreg = my[batch * SEQ + (nt + 1) * F_BN + tid];
        }
        f32x16 a1, a2, a3;
        #pragma unroll
        for (int r = 0; r < 16; ++r) { a1[r]=0.f; a2[r]=0.f; a3[r]=0.f; }
        const int krow = (cw * 32 + l31) * F_KS_STR;
        #pragma unroll
        for (int kk = 0; kk < 16; ++kk) {
            int col = kk * 16 + lh * 8;
            short8 bhi = *(const short8*)&Ks[krow + col];
            short8 blo = *(const short8*)&Ks[krow + 256 + col];
            a1 = __builtin_amdgcn_mfma_f32_32x32x16_bf16(qhi[kk], bhi, a1, 0, 0, 0);
            a2 = __builtin_amdgcn_mfma_f32_32x32x16_bf16(qlo[kk], bhi, a2, 0, 0, 0);
            a3 = __builtin_amdgcn_mfma_f32_32x32x16_bf16(qhi[kk], blo, a3, 0, 0, 0);
        }
        const float mkv = mk[cw * 32 + l31];
        #pragma unroll
        for (int r = 0; r < 16; ++r) {
            float s = a1[r] + a2[r] + a3[r];
            float p = __expf(s - SHIFT) * mkv;
            lsum[r] += p;
            ushort ph = bf16_rn(p);
            ushort pl = bf16_rn(p - bf16_to_f(ph));
            int prow = rw * 32 + (r & 3) + ((r >> 2) << 3) + (lh << 2);
            int pcol = cw * 32 + l31;
            Ps[prow * F_P_STR + pcol] = ph;
            Ps[prow * F_P_STR + 64 + pcol] = pl;
        }
        __syncthreads();
        const int prow = (rw * 32 + l31) * F_P_STR;
        #pragma unroll
        for (int kb = 0; kb < 4; ++kb) {
            int pcol = kb * 16 + lh * 8;
            short8 pa_hi = *(const short8*)&Ps[prow + pcol];
            short8 pa_lo = *(const short8*)&Ps[prow + 64 + pcol];
            #pragma unroll
            for (int t = 0; t < 4; ++t) {
                int d0 = cw * 128 + t * 32 + l31;
                short8 vf;
                #pragma unroll
                for (int j = 0; j < 8; ++j) vf[j] = (short)Ks[(pcol + j) * F_KS_STR + d0];
                oacc[t] = __builtin_amdgcn_mfma_f32_32x32x16_bf16(pa_hi, vf, oacc[t], 0, 0, 0);
                oacc[t] = __builtin_amdgcn_mfma_f32_32x32x16_bf16(pa_lo, vf, oacc[t], 0, 0, 0);
            }
        }
    }
    #pragma unroll
    for (int r = 0; r < 16; ++r) {
        float v = lsum[r];
        v += __shfl_xor(v, 1, 64); v += __shfl_xor(v, 2, 64); v += __shfl_xor(v, 4, 64);
        v += __shfl_xor(v, 8, 64); v += __shfl_xor(v, 16, 64);
        if (l31 == 0) {
            int row = rw * 32 + (r & 3) + ((r >> 2) << 3) + (lh << 2);
            lpart[cw][row] = v;
        }
    }
    __syncthreads();
    if (tid < F_BM) {
        float l = lpart[0][tid] + lpart[1][tid];
        int valid = mx[batch * SEQ + row0 + tid];
        invs[tid] = (valid != 0 && l > 0.f) ? 1.f / l : 0.f;
    }
    __syncthreads();
    float* ob = out + ((size_t)batch * SEQ + row0) * DIM;
    #pragma unroll
    for (int r = 0; r < 16; ++r) {
        int rloc = rw * 32 + (r & 3) + ((r >> 2) << 3) + (lh << 2);
        float inv = invs[rloc];
        #pragma unroll
        for (int t = 0; t < 4; ++t) {
            int d = cw * 128 + t * 32 + l31;
            ob[(size_t)rloc * DIM + d] = oacc[t][r] * inv;
        }
    }
}

extern "C" void kernel_launch(void* const* d_in, const int* in_sizes, int n_in,
                              void* d_out, int out_size, void* d_ws, size_t ws_size,
                              hipStream_t stream) {
    const float* a  = (const float*)d_in[0];
    const float* b  = (const float*)d_in[1];
    const int*   ma = (const int*)d_in[2];
    const int*   mb = (const int*)d_in[3];
    float* out = (float*)d_out;

    if (ws_size >= WS_NEED) {
        char* w = (char*)d_ws;
        ushort* aHI = (ushort*)w;
        ushort* bHI = (ushort*)(w + 16 * 1024 * 1024);
        uchar*  a8  = (uchar*) (w + 32 * 1024 * 1024);
        uchar*  b8  = (uchar*) (w + 48 * 1024 * 1024);
        ushort* aT  = (ushort*)(w + 64 * 1024 * 1024);
        ushort* bT  = (ushort*)(w + 80 * 1024 * 1024);

        prepass<<<dim3(SEQ / 32, NB, 2), 256, 0, stream>>>(a, b, aHI, bHI, a8, b8, aT, bT);
        attend5<<<dim3(1024, 1, 1), 256, 0, stream>>>(aHI, bHI, a8, b8, aT, bT, ma, mb, out);
    } else {
        float* out_a = out;
        float* out_b = out + (size_t)NB * SEQ * DIM;
        dim3 grid(SEQ / F_BM, NB), block(256);
        attend_mfma<<<grid, block, 0, stream>>>(a, b, ma, mb, out_a);
        attend_mfma<<<grid, block, 0, stream>>>(b, a, mb, ma, out_b);
    }
}